// Round 1
// baseline (9348.351 us; speedup 1.0000x reference)
//
#include <hip/hip_runtime.h>
#include <math.h>

__device__ __forceinline__ float sigmoidf_(float x) {
    return 1.0f / (1.0f + __expf(-x));
}

// ---------------- Kernel 1: layer-1 edge scatter ----------------
// msg1[e] = sigmoid(mask[e/2]) * [edge_feat(4) | node_feat[src](7)]
// acc1[dst] += msg1 ; deg[dst] += 1
__global__ void scatter1(const float* __restrict__ edge_feat,
                         const float* __restrict__ edge_mask,
                         const int* __restrict__ src,
                         const int* __restrict__ dst,
                         const float* __restrict__ node_feat,
                         float* __restrict__ acc1,
                         float* __restrict__ deg, int E) {
    int e = blockIdx.x * blockDim.x + threadIdx.x;
    if (e >= E) return;
    float m = sigmoidf_(edge_mask[e >> 1]);
    int s = src[e], d = dst[e];
    float4 ef = *(const float4*)(edge_feat + (size_t)e * 4);
    float* a = acc1 + (size_t)d * 12;
    atomicAdd(a + 0, m * ef.x);
    atomicAdd(a + 1, m * ef.y);
    atomicAdd(a + 2, m * ef.z);
    atomicAdd(a + 3, m * ef.w);
    const float* nf = node_feat + (size_t)s * 7;
#pragma unroll
    for (int j = 0; j < 7; ++j) atomicAdd(a + 4 + j, m * nf[j]);
    atomicAdd(deg + d, 1.0f);
}

// ---------------- Kernel 2: layer-1 node MLP (11->32->32) ----------------
__global__ void mlp1(const float* __restrict__ acc1,
                     const float* __restrict__ deg,
                     const float* __restrict__ W1a, const float* __restrict__ b1a,
                     const float* __restrict__ W1b, const float* __restrict__ b1b,
                     float* __restrict__ h1, int N) {
    __shared__ float sW1a[11 * 32], sb1a[32], sW1b[32 * 32], sb1b[32];
    for (int i = threadIdx.x; i < 11 * 32; i += blockDim.x) sW1a[i] = W1a[i];
    for (int i = threadIdx.x; i < 32 * 32; i += blockDim.x) sW1b[i] = W1b[i];
    if (threadIdx.x < 32) { sb1a[threadIdx.x] = b1a[threadIdx.x]; sb1b[threadIdx.x] = b1b[threadIdx.x]; }
    __syncthreads();
    int n = blockIdx.x * blockDim.x + threadIdx.x;
    if (n >= N) return;
    float inv = 1.0f / fmaxf(deg[n], 1.0f);
    const float* a = acc1 + (size_t)n * 12;
    float x[11];
#pragma unroll
    for (int j = 0; j < 11; ++j) x[j] = a[j] * inv;
    float hdn[32];
#pragma unroll
    for (int k = 0; k < 32; ++k) {
        float acc = sb1a[k];
#pragma unroll
        for (int j = 0; j < 11; ++j) acc += x[j] * sW1a[j * 32 + k];
        hdn[k] = fmaxf(acc, 0.0f);
    }
    float o[32];
#pragma unroll
    for (int k2 = 0; k2 < 32; ++k2) {
        float acc = sb1b[k2];
#pragma unroll
        for (int k = 0; k < 32; ++k) acc += hdn[k] * sW1b[k * 32 + k2];
        o[k2] = fmaxf(acc, 0.0f);
    }
    float4* outp = (float4*)(h1 + (size_t)n * 32);
#pragma unroll
    for (int q = 0; q < 8; ++q)
        outp[q] = make_float4(o[4 * q], o[4 * q + 1], o[4 * q + 2], o[4 * q + 3]);
}

// ---------------- Kernel 3: layer-2 edge scatter ----------------
// 4 threads per edge, each handles 8 of the 32 features.
__global__ void scatter2(const float* __restrict__ edge_mask,
                         const int* __restrict__ src,
                         const int* __restrict__ dst,
                         const float* __restrict__ h1,
                         float* __restrict__ acc2, int E) {
    int t = blockIdx.x * blockDim.x + threadIdx.x;
    int e = t >> 2;
    if (e >= E) return;
    int part = t & 3;
    float m = sigmoidf_(edge_mask[e >> 1]);
    int s = src[e], d = dst[e];
    const float4* hp = (const float4*)(h1 + (size_t)s * 32 + part * 8);
    float4 v0 = hp[0], v1 = hp[1];
    float* a = acc2 + (size_t)d * 32 + part * 8;
    atomicAdd(a + 0, m * v0.x); atomicAdd(a + 1, m * v0.y);
    atomicAdd(a + 2, m * v0.z); atomicAdd(a + 3, m * v0.w);
    atomicAdd(a + 4, m * v1.x); atomicAdd(a + 5, m * v1.y);
    atomicAdd(a + 6, m * v1.z); atomicAdd(a + 7, m * v1.w);
}

// ---------------- Kernel 4: layer-2 node MLP (32->32->32) + global max pool ----------------
__global__ void mlp2max(const float* __restrict__ acc2,
                        const float* __restrict__ deg,
                        const float* __restrict__ W2a, const float* __restrict__ b2a,
                        const float* __restrict__ W2b, const float* __restrict__ b2b,
                        float* __restrict__ gmax, int N) {
    __shared__ float sW2a[32 * 32], sb2a[32], sW2b[32 * 32], sb2b[32];
    __shared__ int smax[32];
    for (int i = threadIdx.x; i < 32 * 32; i += blockDim.x) { sW2a[i] = W2a[i]; sW2b[i] = W2b[i]; }
    if (threadIdx.x < 32) {
        sb2a[threadIdx.x] = b2a[threadIdx.x];
        sb2b[threadIdx.x] = b2b[threadIdx.x];
        smax[threadIdx.x] = 0;
    }
    __syncthreads();
    int n = blockIdx.x * blockDim.x + threadIdx.x;
    bool valid = (n < N);
    int nn = valid ? n : 0;
    float inv = 1.0f / fmaxf(deg[nn], 1.0f);
    const float* a = acc2 + (size_t)nn * 32;
    float x[32];
#pragma unroll
    for (int j = 0; j < 32; ++j) x[j] = a[j] * inv;
    float hdn[32];
#pragma unroll
    for (int k = 0; k < 32; ++k) {
        float acc = sb2a[k];
#pragma unroll
        for (int j = 0; j < 32; ++j) acc += x[j] * sW2a[j * 32 + k];
        hdn[k] = fmaxf(acc, 0.0f);
    }
    int lane = threadIdx.x & 63;
#pragma unroll
    for (int k2 = 0; k2 < 32; ++k2) {
        float acc = sb2b[k2];
#pragma unroll
        for (int k = 0; k < 32; ++k) acc += hdn[k] * sW2b[k * 32 + k2];
        float v = valid ? fmaxf(acc, 0.0f) : 0.0f;
        // wave-64 butterfly max; relu output >= 0 so int-bit compare == float compare
#pragma unroll
        for (int off = 32; off >= 1; off >>= 1)
            v = fmaxf(v, __shfl_xor(v, off));
        if (lane == 0) atomicMax(&smax[k2], __float_as_int(v));
    }
    __syncthreads();
    if (threadIdx.x < 32) atomicMax((int*)&gmax[threadIdx.x], smax[threadIdx.x]);
}

// ---------------- Kernel 5: readout MLP + softmax ----------------
__global__ void readout(const float* __restrict__ gmax,
                        const float* __restrict__ Wm1, const float* __restrict__ bm1,
                        const float* __restrict__ Wm2, const float* __restrict__ bm2,
                        float* __restrict__ out) {
    __shared__ float p[16];
    int t = threadIdx.x;
    if (t < 16) {
        float acc = bm1[t];
        for (int j = 0; j < 32; ++j) acc += gmax[j] * Wm1[j * 16 + t];
        p[t] = fmaxf(acc, 0.0f);
    }
    __syncthreads();
    if (t == 0) {
        float l0 = bm2[0], l1 = bm2[1];
        for (int k = 0; k < 16; ++k) { l0 += p[k] * Wm2[k * 2]; l1 += p[k] * Wm2[k * 2 + 1]; }
        float mx = fmaxf(l0, l1);
        float e0 = __expf(l0 - mx), e1 = __expf(l1 - mx);
        float s = e0 + e1;
        out[0] = e0 / s;
        out[1] = e1 / s;
    }
}

extern "C" void kernel_launch(void* const* d_in, const int* in_sizes, int n_in,
                              void* d_out, int out_size, void* d_ws, size_t ws_size,
                              hipStream_t stream) {
    const float* node_feat = (const float*)d_in[0];
    const float* edge_feat = (const float*)d_in[1];
    const float* edge_mask = (const float*)d_in[2];
    const int*   src       = (const int*)d_in[3];
    const int*   dst       = (const int*)d_in[4];
    const float* W1a = (const float*)d_in[5];
    const float* b1a = (const float*)d_in[6];
    const float* W1b = (const float*)d_in[7];
    const float* b1b = (const float*)d_in[8];
    const float* W2a = (const float*)d_in[9];
    const float* b2a = (const float*)d_in[10];
    const float* W2b = (const float*)d_in[11];
    const float* b2b = (const float*)d_in[12];
    const float* Wm1 = (const float*)d_in[13];
    const float* bm1 = (const float*)d_in[14];
    const float* Wm2 = (const float*)d_in[15];
    const float* bm2 = (const float*)d_in[16];

    const int N = in_sizes[0] / 7;   // 200000
    const int E = in_sizes[3];       // 6400000

    // workspace layout (floats): acc1[N*12] | deg[N] | acc2[N*32] | gmax[32] | h1[N*32]
    float* acc1 = (float*)d_ws;
    float* deg  = acc1 + (size_t)N * 12;
    float* acc2 = deg + N;
    float* gmax = acc2 + (size_t)N * 32;
    float* h1   = gmax + 32;

    // zero acc1 + deg + acc2 + gmax in one contiguous memset (h1 fully overwritten)
    size_t zero_bytes = ((size_t)N * 45 + 32) * sizeof(float);
    hipMemsetAsync(d_ws, 0, zero_bytes, stream);

    scatter1<<<(E + 255) / 256, 256, 0, stream>>>(edge_feat, edge_mask, src, dst,
                                                  node_feat, acc1, deg, E);
    mlp1<<<(N + 255) / 256, 256, 0, stream>>>(acc1, deg, W1a, b1a, W1b, b1b, h1, N);
    scatter2<<<(E * 4 + 255) / 256, 256, 0, stream>>>(edge_mask, src, dst, h1, acc2, E);
    mlp2max<<<(N + 255) / 256, 256, 0, stream>>>(acc2, deg, W2a, b2a, W2b, b2b, gmax, N);
    readout<<<1, 64, 0, stream>>>(gmax, Wm1, bm1, Wm2, bm2, (float*)d_out);
}

// Round 2
// 2617.942 us; speedup vs baseline: 3.5709x; 3.5709x over previous
//
#include <hip/hip_runtime.h>
#include <math.h>

__device__ __forceinline__ float sigmoidf_(float x) {
    return 1.0f / (1.0f + __expf(-x));
}

// ---------------- Kernel 1: in-degree histogram (int atomics) ----------------
__global__ void hist_dst(const int* __restrict__ dst, int* __restrict__ deg, int E) {
    int e = blockIdx.x * blockDim.x + threadIdx.x;
    if (e < E) atomicAdd(&deg[dst[e]], 1);
}

// ---------------- Kernel 2: single-block exclusive scan over 200K counts ----------------
__global__ void scan_deg(const int* __restrict__ deg, int* __restrict__ off,
                         int* __restrict__ cursor, int N) {
    const int T = 1024;
    __shared__ int tmp[T];
    int t = threadIdx.x;
    int chunk = (N + T - 1) / T;
    int lo = t * chunk, hi = min(lo + chunk, N);
    int sum = 0;
    for (int i = lo; i < hi; ++i) sum += deg[i];
    tmp[t] = sum;
    __syncthreads();
    for (int o = 1; o < T; o <<= 1) {
        int v = (t >= o) ? tmp[t - o] : 0;
        __syncthreads();
        tmp[t] += v;
        __syncthreads();
    }
    int run = (t == 0) ? 0 : tmp[t - 1];
    for (int i = lo; i < hi; ++i) { off[i] = run; cursor[i] = run; run += deg[i]; }
    if (t == T - 1) off[N] = tmp[T - 1];
}

// ---------------- Kernel 3: bucket-fill edge ids by dst ----------------
__global__ void fill_csr(const int* __restrict__ dst, int* __restrict__ cursor,
                         int* __restrict__ sorted, int E) {
    int e = blockIdx.x * blockDim.x + threadIdx.x;
    if (e >= E) return;
    int p = atomicAdd(&cursor[dst[e]], 1);
    sorted[p] = e;
}

// ---------------- Kernel 4: fused layer-1 aggregation (gather) + MLP 11->32->32 ----------------
__global__ void agg1_mlp1(const int* __restrict__ sorted, const int* __restrict__ off,
                          const int* __restrict__ deg_i,
                          const float* __restrict__ edge_feat,
                          const float* __restrict__ edge_mask,
                          const int* __restrict__ src,
                          const float* __restrict__ node_feat,
                          const float* __restrict__ W1a, const float* __restrict__ b1a,
                          const float* __restrict__ W1b, const float* __restrict__ b1b,
                          float* __restrict__ h1, int N) {
    __shared__ float sW1a[11 * 32], sb1a[32], sW1b[32 * 32], sb1b[32];
    for (int i = threadIdx.x; i < 11 * 32; i += blockDim.x) sW1a[i] = W1a[i];
    for (int i = threadIdx.x; i < 32 * 32; i += blockDim.x) sW1b[i] = W1b[i];
    if (threadIdx.x < 32) { sb1a[threadIdx.x] = b1a[threadIdx.x]; sb1b[threadIdx.x] = b1b[threadIdx.x]; }
    __syncthreads();
    int n = blockIdx.x * blockDim.x + threadIdx.x;
    if (n >= N) return;
    int deg = deg_i[n];
    int start = off[n];
    float x[11];
#pragma unroll
    for (int j = 0; j < 11; ++j) x[j] = 0.0f;
    for (int i = 0; i < deg; ++i) {
        int e = sorted[start + i];
        float m = sigmoidf_(edge_mask[e >> 1]);
        int s = src[e];
        float4 ef = *(const float4*)(edge_feat + (size_t)e * 4);
        x[0] += m * ef.x; x[1] += m * ef.y; x[2] += m * ef.z; x[3] += m * ef.w;
        const float* nf = node_feat + (size_t)s * 7;
#pragma unroll
        for (int j = 0; j < 7; ++j) x[4 + j] += m * nf[j];
    }
    float inv = 1.0f / fmaxf((float)deg, 1.0f);
#pragma unroll
    for (int j = 0; j < 11; ++j) x[j] *= inv;
    float hdn[32];
#pragma unroll
    for (int k = 0; k < 32; ++k) {
        float acc = sb1a[k];
#pragma unroll
        for (int j = 0; j < 11; ++j) acc += x[j] * sW1a[j * 32 + k];
        hdn[k] = fmaxf(acc, 0.0f);
    }
    float o[32];
#pragma unroll
    for (int k2 = 0; k2 < 32; ++k2) {
        float acc = sb1b[k2];
#pragma unroll
        for (int k = 0; k < 32; ++k) acc += hdn[k] * sW1b[k * 32 + k2];
        o[k2] = fmaxf(acc, 0.0f);
    }
    float4* outp = (float4*)(h1 + (size_t)n * 32);
#pragma unroll
    for (int q = 0; q < 8; ++q)
        outp[q] = make_float4(o[4 * q], o[4 * q + 1], o[4 * q + 2], o[4 * q + 3]);
}

// ---------------- Kernel 5: fused layer-2 aggregation (gather) + MLP + global max pool ----------------
__global__ void agg2_mlp2_max(const int* __restrict__ sorted, const int* __restrict__ off,
                              const int* __restrict__ deg_i,
                              const float* __restrict__ edge_mask,
                              const int* __restrict__ src,
                              const float* __restrict__ h1,
                              const float* __restrict__ W2a, const float* __restrict__ b2a,
                              const float* __restrict__ W2b, const float* __restrict__ b2b,
                              float* __restrict__ gmax, int N) {
    __shared__ float sW2a[32 * 32], sb2a[32], sW2b[32 * 32], sb2b[32];
    __shared__ int smax[32];
    for (int i = threadIdx.x; i < 32 * 32; i += blockDim.x) { sW2a[i] = W2a[i]; sW2b[i] = W2b[i]; }
    if (threadIdx.x < 32) {
        sb2a[threadIdx.x] = b2a[threadIdx.x];
        sb2b[threadIdx.x] = b2b[threadIdx.x];
        smax[threadIdx.x] = 0;
    }
    __syncthreads();
    int n = blockIdx.x * blockDim.x + threadIdx.x;
    bool valid = (n < N);
    int nn = valid ? n : 0;
    int deg = valid ? deg_i[nn] : 0;
    int start = valid ? off[nn] : 0;
    float x[32];
#pragma unroll
    for (int j = 0; j < 32; ++j) x[j] = 0.0f;
    for (int i = 0; i < deg; ++i) {
        int e = sorted[start + i];
        float m = sigmoidf_(edge_mask[e >> 1]);
        int s = src[e];
        const float4* hp = (const float4*)(h1 + (size_t)s * 32);
#pragma unroll
        for (int q = 0; q < 8; ++q) {
            float4 v = hp[q];
            x[4 * q + 0] += m * v.x;
            x[4 * q + 1] += m * v.y;
            x[4 * q + 2] += m * v.z;
            x[4 * q + 3] += m * v.w;
        }
    }
    float inv = 1.0f / fmaxf((float)deg, 1.0f);
#pragma unroll
    for (int j = 0; j < 32; ++j) x[j] *= inv;
    float hdn[32];
#pragma unroll
    for (int k = 0; k < 32; ++k) {
        float acc = sb2a[k];
#pragma unroll
        for (int j = 0; j < 32; ++j) acc += x[j] * sW2a[j * 32 + k];
        hdn[k] = fmaxf(acc, 0.0f);
    }
    int lane = threadIdx.x & 63;
#pragma unroll
    for (int k2 = 0; k2 < 32; ++k2) {
        float acc = sb2b[k2];
#pragma unroll
        for (int k = 0; k < 32; ++k) acc += hdn[k] * sW2b[k * 32 + k2];
        float v = valid ? fmaxf(acc, 0.0f) : 0.0f;
#pragma unroll
        for (int o = 32; o >= 1; o >>= 1)
            v = fmaxf(v, __shfl_xor(v, o));
        if (lane == 0) atomicMax(&smax[k2], __float_as_int(v));
    }
    __syncthreads();
    if (threadIdx.x < 32) atomicMax((int*)&gmax[threadIdx.x], smax[threadIdx.x]);
}

// ---------------- Kernel 6: readout MLP + softmax ----------------
__global__ void readout(const float* __restrict__ gmax,
                        const float* __restrict__ Wm1, const float* __restrict__ bm1,
                        const float* __restrict__ Wm2, const float* __restrict__ bm2,
                        float* __restrict__ out) {
    __shared__ float p[16];
    int t = threadIdx.x;
    if (t < 16) {
        float acc = bm1[t];
        for (int j = 0; j < 32; ++j) acc += gmax[j] * Wm1[j * 16 + t];
        p[t] = fmaxf(acc, 0.0f);
    }
    __syncthreads();
    if (t == 0) {
        float l0 = bm2[0], l1 = bm2[1];
        for (int k = 0; k < 16; ++k) { l0 += p[k] * Wm2[k * 2]; l1 += p[k] * Wm2[k * 2 + 1]; }
        float mx = fmaxf(l0, l1);
        float e0 = __expf(l0 - mx), e1 = __expf(l1 - mx);
        float s = e0 + e1;
        out[0] = e0 / s;
        out[1] = e1 / s;
    }
}

extern "C" void kernel_launch(void* const* d_in, const int* in_sizes, int n_in,
                              void* d_out, int out_size, void* d_ws, size_t ws_size,
                              hipStream_t stream) {
    const float* node_feat = (const float*)d_in[0];
    const float* edge_feat = (const float*)d_in[1];
    const float* edge_mask = (const float*)d_in[2];
    const int*   src       = (const int*)d_in[3];
    const int*   dst       = (const int*)d_in[4];
    const float* W1a = (const float*)d_in[5];
    const float* b1a = (const float*)d_in[6];
    const float* W1b = (const float*)d_in[7];
    const float* b1b = (const float*)d_in[8];
    const float* W2a = (const float*)d_in[9];
    const float* b2a = (const float*)d_in[10];
    const float* W2b = (const float*)d_in[11];
    const float* b2b = (const float*)d_in[12];
    const float* Wm1 = (const float*)d_in[13];
    const float* bm1 = (const float*)d_in[14];
    const float* Wm2 = (const float*)d_in[15];
    const float* bm2 = (const float*)d_in[16];

    const int N = in_sizes[0] / 7;   // 200000
    const int E = in_sizes[3];       // 6400000

    // workspace layout:
    // [deg_i: N int][gmax: 32 f][off: N+1 int][cursor: N int][sorted: E int][h1: N*32 f]
    int*   deg_i  = (int*)d_ws;
    float* gmax   = (float*)(deg_i + N);
    int*   off    = (int*)(gmax + 32);
    int*   cursor = off + (N + 1);
    int*   sorted = cursor + N;
    float* h1     = (float*)(sorted + E);

    // zero only deg_i + gmax (contiguous head); everything else fully overwritten
    hipMemsetAsync(d_ws, 0, (size_t)(N + 32) * sizeof(float), stream);

    hist_dst<<<(E + 255) / 256, 256, 0, stream>>>(dst, deg_i, E);
    scan_deg<<<1, 1024, 0, stream>>>(deg_i, off, cursor, N);
    fill_csr<<<(E + 255) / 256, 256, 0, stream>>>(dst, cursor, sorted, E);
    agg1_mlp1<<<(N + 255) / 256, 256, 0, stream>>>(sorted, off, deg_i,
                                                   edge_feat, edge_mask, src, node_feat,
                                                   W1a, b1a, W1b, b1b, h1, N);
    agg2_mlp2_max<<<(N + 255) / 256, 256, 0, stream>>>(sorted, off, deg_i,
                                                       edge_mask, src, h1,
                                                       W2a, b2a, W2b, b2b, gmax, N);
    readout<<<1, 64, 0, stream>>>(gmax, Wm1, bm1, Wm2, bm2, (float*)d_out);
}

// Round 3
// 1608.356 us; speedup vs baseline: 5.8124x; 1.6277x over previous
//
#include <hip/hip_runtime.h>
#include <math.h>

__device__ __forceinline__ float sigmoidf_(float x) {
    return 1.0f / (1.0f + __expf(-x));
}

// ---------------- hist + rank: deg[dst]++ and remember each edge's arrival rank ----------------
__global__ void hist_rank(const int* __restrict__ dst, int* __restrict__ deg,
                          int* __restrict__ rank, int E) {
    int e = blockIdx.x * blockDim.x + threadIdx.x;
    if (e < E) rank[e] = atomicAdd(&deg[dst[e]], 1);
}

// ---------------- single-block exclusive scan over N counts ----------------
__global__ void scan_deg(const int* __restrict__ deg, int* __restrict__ off, int N) {
    const int T = 1024;
    __shared__ int tmp[T];
    int t = threadIdx.x;
    int chunk = (N + T - 1) / T;
    int lo = t * chunk, hi = min(lo + chunk, N);
    int sum = 0;
    for (int i = lo; i < hi; ++i) sum += deg[i];
    tmp[t] = sum;
    __syncthreads();
    for (int o = 1; o < T; o <<= 1) {
        int v = (t >= o) ? tmp[t - o] : 0;
        __syncthreads();
        tmp[t] += v;
        __syncthreads();
    }
    int run = (t == 0) ? 0 : tmp[t - 1];
    for (int i = lo; i < hi; ++i) { off[i] = run; run += deg[i]; }
    if (t == T - 1) off[N] = tmp[T - 1];
}

// ======================= Plan A: 8B records {e, packed(src,m)} =======================
__global__ void fill_rec(const int* __restrict__ dst, const int* __restrict__ rank,
                         const int* __restrict__ off,
                         const float* __restrict__ edge_mask,
                         const int* __restrict__ src,
                         int2* __restrict__ rec, int E) {
    int e = blockIdx.x * blockDim.x + threadIdx.x;
    if (e >= E) return;
    int p = off[dst[e]] + rank[e];          // no atomics
    float m = sigmoidf_(edge_mask[e >> 1]);
    int mq = (int)(m * 16384.0f + 0.5f);
    mq = min(mq, 16383);
    unsigned packed = ((unsigned)src[e] << 14) | (unsigned)mq;
    rec[p] = make_int2(e, (int)packed);
}

__global__ void agg1_rec(const int2* __restrict__ rec, const int* __restrict__ off,
                         const int* __restrict__ deg_i,
                         const float* __restrict__ edge_feat,
                         const float* __restrict__ node_feat,
                         const float* __restrict__ W1a, const float* __restrict__ b1a,
                         const float* __restrict__ W1b, const float* __restrict__ b1b,
                         float* __restrict__ h1, int N) {
    __shared__ float sW1a[11 * 32], sb1a[32], sW1b[32 * 32], sb1b[32];
    for (int i = threadIdx.x; i < 11 * 32; i += blockDim.x) sW1a[i] = W1a[i];
    for (int i = threadIdx.x; i < 32 * 32; i += blockDim.x) sW1b[i] = W1b[i];
    if (threadIdx.x < 32) { sb1a[threadIdx.x] = b1a[threadIdx.x]; sb1b[threadIdx.x] = b1b[threadIdx.x]; }
    __syncthreads();
    int n = blockIdx.x * blockDim.x + threadIdx.x;
    if (n >= N) return;
    int deg = deg_i[n];
    int start = off[n];
    float x[11];
#pragma unroll
    for (int j = 0; j < 11; ++j) x[j] = 0.0f;
    for (int i = 0; i < deg; ++i) {
        int2 r = rec[start + i];
        int e = r.x;
        unsigned packed = (unsigned)r.y;
        int s = (int)(packed >> 14);
        float m = (float)(packed & 16383u) * (1.0f / 16384.0f);
        float4 ef = *(const float4*)(edge_feat + (size_t)e * 4);
        x[0] += m * ef.x; x[1] += m * ef.y; x[2] += m * ef.z; x[3] += m * ef.w;
        const float* nf = node_feat + (size_t)s * 7;
#pragma unroll
        for (int j = 0; j < 7; ++j) x[4 + j] += m * nf[j];
    }
    float inv = 1.0f / fmaxf((float)deg, 1.0f);
#pragma unroll
    for (int j = 0; j < 11; ++j) x[j] *= inv;
    float hdn[32];
#pragma unroll
    for (int k = 0; k < 32; ++k) {
        float acc = sb1a[k];
#pragma unroll
        for (int j = 0; j < 11; ++j) acc += x[j] * sW1a[j * 32 + k];
        hdn[k] = fmaxf(acc, 0.0f);
    }
    float o[32];
#pragma unroll
    for (int k2 = 0; k2 < 32; ++k2) {
        float acc = sb1b[k2];
#pragma unroll
        for (int k = 0; k < 32; ++k) acc += hdn[k] * sW1b[k * 32 + k2];
        o[k2] = fmaxf(acc, 0.0f);
    }
    float4* outp = (float4*)(h1 + (size_t)n * 32);
#pragma unroll
    for (int q = 0; q < 8; ++q)
        outp[q] = make_float4(o[4 * q], o[4 * q + 1], o[4 * q + 2], o[4 * q + 3]);
}

__global__ void agg2_rec(const int2* __restrict__ rec, const int* __restrict__ off,
                         const int* __restrict__ deg_i,
                         const float* __restrict__ h1,
                         const float* __restrict__ W2a, const float* __restrict__ b2a,
                         const float* __restrict__ W2b, const float* __restrict__ b2b,
                         float* __restrict__ gmax, int N) {
    __shared__ float sW2a[32 * 32], sb2a[32], sW2b[32 * 32], sb2b[32];
    __shared__ int smax[32];
    for (int i = threadIdx.x; i < 32 * 32; i += blockDim.x) { sW2a[i] = W2a[i]; sW2b[i] = W2b[i]; }
    if (threadIdx.x < 32) {
        sb2a[threadIdx.x] = b2a[threadIdx.x];
        sb2b[threadIdx.x] = b2b[threadIdx.x];
        smax[threadIdx.x] = 0;
    }
    __syncthreads();
    int n = blockIdx.x * blockDim.x + threadIdx.x;
    bool valid = (n < N);
    int nn = valid ? n : 0;
    int deg = valid ? deg_i[nn] : 0;
    int start = valid ? off[nn] : 0;
    float x[32];
#pragma unroll
    for (int j = 0; j < 32; ++j) x[j] = 0.0f;
    for (int i = 0; i < deg; ++i) {
        int2 r = rec[start + i];
        unsigned packed = (unsigned)r.y;
        int s = (int)(packed >> 14);
        float m = (float)(packed & 16383u) * (1.0f / 16384.0f);
        const float4* hp = (const float4*)(h1 + (size_t)s * 32);
#pragma unroll
        for (int q = 0; q < 8; ++q) {
            float4 v = hp[q];
            x[4 * q + 0] += m * v.x;
            x[4 * q + 1] += m * v.y;
            x[4 * q + 2] += m * v.z;
            x[4 * q + 3] += m * v.w;
        }
    }
    float inv = 1.0f / fmaxf((float)deg, 1.0f);
#pragma unroll
    for (int j = 0; j < 32; ++j) x[j] *= inv;
    float hdn[32];
#pragma unroll
    for (int k = 0; k < 32; ++k) {
        float acc = sb2a[k];
#pragma unroll
        for (int j = 0; j < 32; ++j) acc += x[j] * sW2a[j * 32 + k];
        hdn[k] = fmaxf(acc, 0.0f);
    }
    int lane = threadIdx.x & 63;
#pragma unroll
    for (int k2 = 0; k2 < 32; ++k2) {
        float acc = sb2b[k2];
#pragma unroll
        for (int k = 0; k < 32; ++k) acc += hdn[k] * sW2b[k * 32 + k2];
        float v = valid ? fmaxf(acc, 0.0f) : 0.0f;
#pragma unroll
        for (int o = 32; o >= 1; o >>= 1)
            v = fmaxf(v, __shfl_xor(v, o));
        if (lane == 0) atomicMax(&smax[k2], __float_as_int(v));
    }
    __syncthreads();
    if (threadIdx.x < 32) atomicMax((int*)&gmax[threadIdx.x], smax[threadIdx.x]);
}

// ======================= Fallback (round-2 style, 53 MB): sorted e only =======================
__global__ void fill_sorted(const int* __restrict__ dst, const int* __restrict__ rank,
                            const int* __restrict__ off, int* __restrict__ sorted, int E) {
    int e = blockIdx.x * blockDim.x + threadIdx.x;
    if (e >= E) return;
    sorted[off[dst[e]] + rank[e]] = e;
}

__global__ void agg1_mlp1(const int* __restrict__ sorted, const int* __restrict__ off,
                          const int* __restrict__ deg_i,
                          const float* __restrict__ edge_feat,
                          const float* __restrict__ edge_mask,
                          const int* __restrict__ src,
                          const float* __restrict__ node_feat,
                          const float* __restrict__ W1a, const float* __restrict__ b1a,
                          const float* __restrict__ W1b, const float* __restrict__ b1b,
                          float* __restrict__ h1, int N) {
    __shared__ float sW1a[11 * 32], sb1a[32], sW1b[32 * 32], sb1b[32];
    for (int i = threadIdx.x; i < 11 * 32; i += blockDim.x) sW1a[i] = W1a[i];
    for (int i = threadIdx.x; i < 32 * 32; i += blockDim.x) sW1b[i] = W1b[i];
    if (threadIdx.x < 32) { sb1a[threadIdx.x] = b1a[threadIdx.x]; sb1b[threadIdx.x] = b1b[threadIdx.x]; }
    __syncthreads();
    int n = blockIdx.x * blockDim.x + threadIdx.x;
    if (n >= N) return;
    int deg = deg_i[n];
    int start = off[n];
    float x[11];
#pragma unroll
    for (int j = 0; j < 11; ++j) x[j] = 0.0f;
    for (int i = 0; i < deg; ++i) {
        int e = sorted[start + i];
        float m = sigmoidf_(edge_mask[e >> 1]);
        int s = src[e];
        float4 ef = *(const float4*)(edge_feat + (size_t)e * 4);
        x[0] += m * ef.x; x[1] += m * ef.y; x[2] += m * ef.z; x[3] += m * ef.w;
        const float* nf = node_feat + (size_t)s * 7;
#pragma unroll
        for (int j = 0; j < 7; ++j) x[4 + j] += m * nf[j];
    }
    float inv = 1.0f / fmaxf((float)deg, 1.0f);
#pragma unroll
    for (int j = 0; j < 11; ++j) x[j] *= inv;
    float hdn[32];
#pragma unroll
    for (int k = 0; k < 32; ++k) {
        float acc = sb1a[k];
#pragma unroll
        for (int j = 0; j < 11; ++j) acc += x[j] * sW1a[j * 32 + k];
        hdn[k] = fmaxf(acc, 0.0f);
    }
    float o[32];
#pragma unroll
    for (int k2 = 0; k2 < 32; ++k2) {
        float acc = sb1b[k2];
#pragma unroll
        for (int k = 0; k < 32; ++k) acc += hdn[k] * sW1b[k * 32 + k2];
        o[k2] = fmaxf(acc, 0.0f);
    }
    float4* outp = (float4*)(h1 + (size_t)n * 32);
#pragma unroll
    for (int q = 0; q < 8; ++q)
        outp[q] = make_float4(o[4 * q], o[4 * q + 1], o[4 * q + 2], o[4 * q + 3]);
}

__global__ void agg2_mlp2_max(const int* __restrict__ sorted, const int* __restrict__ off,
                              const int* __restrict__ deg_i,
                              const float* __restrict__ edge_mask,
                              const int* __restrict__ src,
                              const float* __restrict__ h1,
                              const float* __restrict__ W2a, const float* __restrict__ b2a,
                              const float* __restrict__ W2b, const float* __restrict__ b2b,
                              float* __restrict__ gmax, int N) {
    __shared__ float sW2a[32 * 32], sb2a[32], sW2b[32 * 32], sb2b[32];
    __shared__ int smax[32];
    for (int i = threadIdx.x; i < 32 * 32; i += blockDim.x) { sW2a[i] = W2a[i]; sW2b[i] = W2b[i]; }
    if (threadIdx.x < 32) {
        sb2a[threadIdx.x] = b2a[threadIdx.x];
        sb2b[threadIdx.x] = b2b[threadIdx.x];
        smax[threadIdx.x] = 0;
    }
    __syncthreads();
    int n = blockIdx.x * blockDim.x + threadIdx.x;
    bool valid = (n < N);
    int nn = valid ? n : 0;
    int deg = valid ? deg_i[nn] : 0;
    int start = valid ? off[nn] : 0;
    float x[32];
#pragma unroll
    for (int j = 0; j < 32; ++j) x[j] = 0.0f;
    for (int i = 0; i < deg; ++i) {
        int e = sorted[start + i];
        float m = sigmoidf_(edge_mask[e >> 1]);
        int s = src[e];
        const float4* hp = (const float4*)(h1 + (size_t)s * 32);
#pragma unroll
        for (int q = 0; q < 8; ++q) {
            float4 v = hp[q];
            x[4 * q + 0] += m * v.x;
            x[4 * q + 1] += m * v.y;
            x[4 * q + 2] += m * v.z;
            x[4 * q + 3] += m * v.w;
        }
    }
    float inv = 1.0f / fmaxf((float)deg, 1.0f);
#pragma unroll
    for (int j = 0; j < 32; ++j) x[j] *= inv;
    float hdn[32];
#pragma unroll
    for (int k = 0; k < 32; ++k) {
        float acc = sb2a[k];
#pragma unroll
        for (int j = 0; j < 32; ++j) acc += x[j] * sW2a[j * 32 + k];
        hdn[k] = fmaxf(acc, 0.0f);
    }
    int lane = threadIdx.x & 63;
#pragma unroll
    for (int k2 = 0; k2 < 32; ++k2) {
        float acc = sb2b[k2];
#pragma unroll
        for (int k = 0; k < 32; ++k) acc += hdn[k] * sW2b[k * 32 + k2];
        float v = valid ? fmaxf(acc, 0.0f) : 0.0f;
#pragma unroll
        for (int o = 32; o >= 1; o >>= 1)
            v = fmaxf(v, __shfl_xor(v, o));
        if (lane == 0) atomicMax(&smax[k2], __float_as_int(v));
    }
    __syncthreads();
    if (threadIdx.x < 32) atomicMax((int*)&gmax[threadIdx.x], smax[threadIdx.x]);
}

// ---------------- readout MLP + softmax ----------------
__global__ void readout(const float* __restrict__ gmax,
                        const float* __restrict__ Wm1, const float* __restrict__ bm1,
                        const float* __restrict__ Wm2, const float* __restrict__ bm2,
                        float* __restrict__ out) {
    __shared__ float p[16];
    int t = threadIdx.x;
    if (t < 16) {
        float acc = bm1[t];
        for (int j = 0; j < 32; ++j) acc += gmax[j] * Wm1[j * 16 + t];
        p[t] = fmaxf(acc, 0.0f);
    }
    __syncthreads();
    if (t == 0) {
        float l0 = bm2[0], l1 = bm2[1];
        for (int k = 0; k < 16; ++k) { l0 += p[k] * Wm2[k * 2]; l1 += p[k] * Wm2[k * 2 + 1]; }
        float mx = fmaxf(l0, l1);
        float e0 = __expf(l0 - mx), e1 = __expf(l1 - mx);
        float s = e0 + e1;
        out[0] = e0 / s;
        out[1] = e1 / s;
    }
}

extern "C" void kernel_launch(void* const* d_in, const int* in_sizes, int n_in,
                              void* d_out, int out_size, void* d_ws, size_t ws_size,
                              hipStream_t stream) {
    const float* node_feat = (const float*)d_in[0];
    const float* edge_feat = (const float*)d_in[1];
    const float* edge_mask = (const float*)d_in[2];
    const int*   src       = (const int*)d_in[3];
    const int*   dst       = (const int*)d_in[4];
    const float* W1a = (const float*)d_in[5];
    const float* b1a = (const float*)d_in[6];
    const float* W1b = (const float*)d_in[7];
    const float* b1b = (const float*)d_in[8];
    const float* W2a = (const float*)d_in[9];
    const float* b2a = (const float*)d_in[10];
    const float* W2b = (const float*)d_in[11];
    const float* b2b = (const float*)d_in[12];
    const float* Wm1 = (const float*)d_in[13];
    const float* bm1 = (const float*)d_in[14];
    const float* Wm2 = (const float*)d_in[15];
    const float* bm2 = (const float*)d_in[16];

    const int N = in_sizes[0] / 7;   // 200000
    const int E = in_sizes[3];       // 6400000

    const size_t shared_len = (size_t)E > (size_t)32 * N ? (size_t)E : (size_t)32 * N;

    // common head: deg_i[N] | gmax[32] | off[N+1]
    int*   deg_i = (int*)d_ws;
    float* gmax  = (float*)(deg_i + N);
    int*   off   = (int*)(gmax + 32);
    int*   shared_slot = off + (N + 1);          // rank (until fill) then h1 (after agg1)
    int*   rank  = shared_slot;
    float* h1    = (float*)shared_slot;
    int*   tail  = shared_slot + shared_len;     // rec (planA) or sorted (fallback)

    const size_t headwords = (size_t)N + 32 + (N + 1) + shared_len;
    const size_t needA = (headwords + (size_t)E * 2) * sizeof(int);   // rec = int2
    const size_t needB = (headwords + (size_t)E) * sizeof(int);       // sorted = int

    // zero deg_i + gmax (contiguous head)
    hipMemsetAsync(d_ws, 0, (size_t)(N + 32) * sizeof(int), stream);

    hist_rank<<<(E + 255) / 256, 256, 0, stream>>>(dst, deg_i, rank, E);
    scan_deg<<<1, 1024, 0, stream>>>(deg_i, off, N);

    if (ws_size >= needA) {
        int2* rec = (int2*)tail;
        fill_rec<<<(E + 255) / 256, 256, 0, stream>>>(dst, rank, off, edge_mask, src, rec, E);
        agg1_rec<<<(N + 255) / 256, 256, 0, stream>>>(rec, off, deg_i, edge_feat, node_feat,
                                                      W1a, b1a, W1b, b1b, h1, N);
        agg2_rec<<<(N + 255) / 256, 256, 0, stream>>>(rec, off, deg_i, h1,
                                                      W2a, b2a, W2b, b2b, gmax, N);
    } else if (ws_size >= needB) {
        int* sorted = tail;
        fill_sorted<<<(E + 255) / 256, 256, 0, stream>>>(dst, rank, off, sorted, E);
        agg1_mlp1<<<(N + 255) / 256, 256, 0, stream>>>(sorted, off, deg_i,
                                                       edge_feat, edge_mask, src, node_feat,
                                                       W1a, b1a, W1b, b1b, h1, N);
        agg2_mlp2_max<<<(N + 255) / 256, 256, 0, stream>>>(sorted, off, deg_i,
                                                           edge_mask, src, h1,
                                                           W2a, b2a, W2b, b2b, gmax, N);
    }
    readout<<<1, 64, 0, stream>>>(gmax, Wm1, bm1, Wm2, bm2, (float*)d_out);
}

// Round 4
// 1451.182 us; speedup vs baseline: 6.4419x; 1.1083x over previous
//
#include <hip/hip_runtime.h>
#include <hip/hip_fp16.h>
#include <math.h>

__device__ __forceinline__ float sigmoidf_(float x) {
    return 1.0f / (1.0f + __expf(-x));
}

union I2H { int i; __half2 h; };
__device__ __forceinline__ int pack_h2(float a, float b) {
    I2H u; u.h = __floats2half2_rn(a, b); return u.i;
}
__device__ __forceinline__ float2 unpack_h2(int w) {
    I2H u; u.i = w; return __half22float2(u.h);
}

// ---------------- hist + rank ----------------
__global__ void hist_rank(const int* __restrict__ dst, int* __restrict__ deg,
                          int* __restrict__ rank, int E) {
    int e = blockIdx.x * blockDim.x + threadIdx.x;
    if (e < E) rank[e] = atomicAdd(&deg[dst[e]], 1);
}

// ---------------- single-block exclusive scan ----------------
__global__ void scan_deg(const int* __restrict__ deg, int* __restrict__ off, int N) {
    const int T = 1024;
    __shared__ int tmp[T];
    int t = threadIdx.x;
    int chunk = (N + T - 1) / T;
    int lo = t * chunk, hi = min(lo + chunk, N);
    int sum = 0;
    for (int i = lo; i < hi; ++i) sum += deg[i];
    tmp[t] = sum;
    __syncthreads();
    for (int o = 1; o < T; o <<= 1) {
        int v = (t >= o) ? tmp[t - o] : 0;
        __syncthreads();
        tmp[t] += v;
        __syncthreads();
    }
    int run = (t == 0) ? 0 : tmp[t - 1];
    for (int i = lo; i < hi; ++i) { off[i] = run; run += deg[i]; }
    if (t == T - 1) off[N] = tmp[T - 1];
}

// ======================= Plan A16: 16B records {src, h2(m*ef01), h2(m*ef23), m} =======================
__global__ void pack_nodes(const float* __restrict__ nf, int4* __restrict__ nf16, int N) {
    int n = blockIdx.x * blockDim.x + threadIdx.x;
    if (n >= N) return;
    const float* p = nf + (size_t)n * 7;
    int4 w;
    w.x = pack_h2(p[0], p[1]);
    w.y = pack_h2(p[2], p[3]);
    w.z = pack_h2(p[4], p[5]);
    w.w = pack_h2(p[6], 0.0f);
    nf16[n] = w;
}

__global__ void fill_rec16(const int* __restrict__ dst, const int* __restrict__ rank,
                           const int* __restrict__ off,
                           const float* __restrict__ edge_mask,
                           const int* __restrict__ src,
                           const float* __restrict__ edge_feat,
                           int4* __restrict__ rec, int E) {
    int e = blockIdx.x * blockDim.x + threadIdx.x;
    if (e >= E) return;
    int p = off[dst[e]] + rank[e];          // no atomics
    float m = sigmoidf_(edge_mask[e >> 1]);
    float4 ef = *(const float4*)(edge_feat + (size_t)e * 4);
    int4 w;
    w.x = src[e];
    w.y = pack_h2(m * ef.x, m * ef.y);
    w.z = pack_h2(m * ef.z, m * ef.w);
    w.w = __float_as_int(m);
    rec[p] = w;
}

__global__ void agg1_16(const int4* __restrict__ rec, const int* __restrict__ off,
                        const int4* __restrict__ nf16,
                        const float* __restrict__ W1a, const float* __restrict__ b1a,
                        const float* __restrict__ W1b, const float* __restrict__ b1b,
                        __half* __restrict__ h1h, int N) {
    __shared__ float sW1a[11 * 32], sb1a[32], sW1b[32 * 32], sb1b[32];
    for (int i = threadIdx.x; i < 11 * 32; i += blockDim.x) sW1a[i] = W1a[i];
    for (int i = threadIdx.x; i < 32 * 32; i += blockDim.x) sW1b[i] = W1b[i];
    if (threadIdx.x < 32) { sb1a[threadIdx.x] = b1a[threadIdx.x]; sb1b[threadIdx.x] = b1b[threadIdx.x]; }
    __syncthreads();
    int n = blockIdx.x * blockDim.x + threadIdx.x;
    if (n >= N) return;
    int start = off[n];
    int deg = off[n + 1] - start;
    float x[11];
#pragma unroll
    for (int j = 0; j < 11; ++j) x[j] = 0.0f;
    for (int i = 0; i < deg; ++i) {
        int4 r = rec[start + i];
        float m = __int_as_float(r.w);
        float2 e01 = unpack_h2(r.y), e23 = unpack_h2(r.z);
        x[0] += e01.x; x[1] += e01.y; x[2] += e23.x; x[3] += e23.y;
        int4 nw = nf16[r.x];
        float2 n01 = unpack_h2(nw.x), n23 = unpack_h2(nw.y);
        float2 n45 = unpack_h2(nw.z), n6 = unpack_h2(nw.w);
        x[4] += m * n01.x; x[5]  += m * n01.y; x[6] += m * n23.x; x[7] += m * n23.y;
        x[8] += m * n45.x; x[9]  += m * n45.y; x[10] += m * n6.x;
    }
    float inv = 1.0f / fmaxf((float)deg, 1.0f);
#pragma unroll
    for (int j = 0; j < 11; ++j) x[j] *= inv;
    float hdn[32];
#pragma unroll
    for (int k = 0; k < 32; ++k) {
        float acc = sb1a[k];
#pragma unroll
        for (int j = 0; j < 11; ++j) acc += x[j] * sW1a[j * 32 + k];
        hdn[k] = fmaxf(acc, 0.0f);
    }
    float o[32];
#pragma unroll
    for (int k2 = 0; k2 < 32; ++k2) {
        float acc = sb1b[k2];
#pragma unroll
        for (int k = 0; k < 32; ++k) acc += hdn[k] * sW1b[k * 32 + k2];
        o[k2] = fmaxf(acc, 0.0f);
    }
    int4* outp = (int4*)(h1h + (size_t)n * 32);
#pragma unroll
    for (int q = 0; q < 4; ++q) {
        int4 w;
        w.x = pack_h2(o[8 * q + 0], o[8 * q + 1]);
        w.y = pack_h2(o[8 * q + 2], o[8 * q + 3]);
        w.z = pack_h2(o[8 * q + 4], o[8 * q + 5]);
        w.w = pack_h2(o[8 * q + 6], o[8 * q + 7]);
        outp[q] = w;
    }
}

__global__ void agg2_16(const int4* __restrict__ rec, const int* __restrict__ off,
                        const __half* __restrict__ h1h,
                        const float* __restrict__ W2a, const float* __restrict__ b2a,
                        const float* __restrict__ W2b, const float* __restrict__ b2b,
                        float* __restrict__ gmax, int N) {
    __shared__ float sW2a[32 * 32], sb2a[32], sW2b[32 * 32], sb2b[32];
    __shared__ int smax[32];
    for (int i = threadIdx.x; i < 32 * 32; i += blockDim.x) { sW2a[i] = W2a[i]; sW2b[i] = W2b[i]; }
    if (threadIdx.x < 32) {
        sb2a[threadIdx.x] = b2a[threadIdx.x];
        sb2b[threadIdx.x] = b2b[threadIdx.x];
        smax[threadIdx.x] = 0;
    }
    __syncthreads();
    int n = blockIdx.x * blockDim.x + threadIdx.x;
    bool valid = (n < N);
    int nn = valid ? n : 0;
    int start = valid ? off[nn] : 0;
    int deg = valid ? (off[nn + 1] - start) : 0;
    float x[32];
#pragma unroll
    for (int j = 0; j < 32; ++j) x[j] = 0.0f;
    for (int i = 0; i < deg; ++i) {
        int4 r = rec[start + i];
        int s = r.x;
        float m = __int_as_float(r.w);
        const int4* hp = (const int4*)(h1h + (size_t)s * 32);
#pragma unroll
        for (int q = 0; q < 4; ++q) {
            int4 v = hp[q];
            float2 a = unpack_h2(v.x), b = unpack_h2(v.y);
            float2 c = unpack_h2(v.z), d = unpack_h2(v.w);
            x[8 * q + 0] += m * a.x; x[8 * q + 1] += m * a.y;
            x[8 * q + 2] += m * b.x; x[8 * q + 3] += m * b.y;
            x[8 * q + 4] += m * c.x; x[8 * q + 5] += m * c.y;
            x[8 * q + 6] += m * d.x; x[8 * q + 7] += m * d.y;
        }
    }
    float inv = 1.0f / fmaxf((float)deg, 1.0f);
#pragma unroll
    for (int j = 0; j < 32; ++j) x[j] *= inv;
    float hdn[32];
#pragma unroll
    for (int k = 0; k < 32; ++k) {
        float acc = sb2a[k];
#pragma unroll
        for (int j = 0; j < 32; ++j) acc += x[j] * sW2a[j * 32 + k];
        hdn[k] = fmaxf(acc, 0.0f);
    }
    int lane = threadIdx.x & 63;
#pragma unroll
    for (int k2 = 0; k2 < 32; ++k2) {
        float acc = sb2b[k2];
#pragma unroll
        for (int k = 0; k < 32; ++k) acc += hdn[k] * sW2b[k * 32 + k2];
        float v = valid ? fmaxf(acc, 0.0f) : 0.0f;
#pragma unroll
        for (int o = 32; o >= 1; o >>= 1)
            v = fmaxf(v, __shfl_xor(v, o));
        if (lane == 0) atomicMax(&smax[k2], __float_as_int(v));
    }
    __syncthreads();
    if (threadIdx.x < 32) atomicMax((int*)&gmax[threadIdx.x], smax[threadIdx.x]);
}

// ======================= Fallback Plan A8 (round-3, proven to fit) =======================
__global__ void fill_rec(const int* __restrict__ dst, const int* __restrict__ rank,
                         const int* __restrict__ off,
                         const float* __restrict__ edge_mask,
                         const int* __restrict__ src,
                         int2* __restrict__ rec, int E) {
    int e = blockIdx.x * blockDim.x + threadIdx.x;
    if (e >= E) return;
    int p = off[dst[e]] + rank[e];
    float m = sigmoidf_(edge_mask[e >> 1]);
    int mq = (int)(m * 16384.0f + 0.5f);
    mq = min(mq, 16383);
    unsigned packed = ((unsigned)src[e] << 14) | (unsigned)mq;
    rec[p] = make_int2(e, (int)packed);
}

__global__ void agg1_rec(const int2* __restrict__ rec, const int* __restrict__ off,
                         const float* __restrict__ edge_feat,
                         const float* __restrict__ node_feat,
                         const float* __restrict__ W1a, const float* __restrict__ b1a,
                         const float* __restrict__ W1b, const float* __restrict__ b1b,
                         float* __restrict__ h1, int N) {
    __shared__ float sW1a[11 * 32], sb1a[32], sW1b[32 * 32], sb1b[32];
    for (int i = threadIdx.x; i < 11 * 32; i += blockDim.x) sW1a[i] = W1a[i];
    for (int i = threadIdx.x; i < 32 * 32; i += blockDim.x) sW1b[i] = W1b[i];
    if (threadIdx.x < 32) { sb1a[threadIdx.x] = b1a[threadIdx.x]; sb1b[threadIdx.x] = b1b[threadIdx.x]; }
    __syncthreads();
    int n = blockIdx.x * blockDim.x + threadIdx.x;
    if (n >= N) return;
    int start = off[n];
    int deg = off[n + 1] - start;
    float x[11];
#pragma unroll
    for (int j = 0; j < 11; ++j) x[j] = 0.0f;
    for (int i = 0; i < deg; ++i) {
        int2 r = rec[start + i];
        int e = r.x;
        unsigned packed = (unsigned)r.y;
        int s = (int)(packed >> 14);
        float m = (float)(packed & 16383u) * (1.0f / 16384.0f);
        float4 ef = *(const float4*)(edge_feat + (size_t)e * 4);
        x[0] += m * ef.x; x[1] += m * ef.y; x[2] += m * ef.z; x[3] += m * ef.w;
        const float* nf = node_feat + (size_t)s * 7;
#pragma unroll
        for (int j = 0; j < 7; ++j) x[4 + j] += m * nf[j];
    }
    float inv = 1.0f / fmaxf((float)deg, 1.0f);
#pragma unroll
    for (int j = 0; j < 11; ++j) x[j] *= inv;
    float hdn[32];
#pragma unroll
    for (int k = 0; k < 32; ++k) {
        float acc = sb1a[k];
#pragma unroll
        for (int j = 0; j < 11; ++j) acc += x[j] * sW1a[j * 32 + k];
        hdn[k] = fmaxf(acc, 0.0f);
    }
    float o[32];
#pragma unroll
    for (int k2 = 0; k2 < 32; ++k2) {
        float acc = sb1b[k2];
#pragma unroll
        for (int k = 0; k < 32; ++k) acc += hdn[k] * sW1b[k * 32 + k2];
        o[k2] = fmaxf(acc, 0.0f);
    }
    float4* outp = (float4*)(h1 + (size_t)n * 32);
#pragma unroll
    for (int q = 0; q < 8; ++q)
        outp[q] = make_float4(o[4 * q], o[4 * q + 1], o[4 * q + 2], o[4 * q + 3]);
}

__global__ void agg2_rec(const int2* __restrict__ rec, const int* __restrict__ off,
                         const float* __restrict__ h1,
                         const float* __restrict__ W2a, const float* __restrict__ b2a,
                         const float* __restrict__ W2b, const float* __restrict__ b2b,
                         float* __restrict__ gmax, int N) {
    __shared__ float sW2a[32 * 32], sb2a[32], sW2b[32 * 32], sb2b[32];
    __shared__ int smax[32];
    for (int i = threadIdx.x; i < 32 * 32; i += blockDim.x) { sW2a[i] = W2a[i]; sW2b[i] = W2b[i]; }
    if (threadIdx.x < 32) {
        sb2a[threadIdx.x] = b2a[threadIdx.x];
        sb2b[threadIdx.x] = b2b[threadIdx.x];
        smax[threadIdx.x] = 0;
    }
    __syncthreads();
    int n = blockIdx.x * blockDim.x + threadIdx.x;
    bool valid = (n < N);
    int nn = valid ? n : 0;
    int start = valid ? off[nn] : 0;
    int deg = valid ? (off[nn + 1] - start) : 0;
    float x[32];
#pragma unroll
    for (int j = 0; j < 32; ++j) x[j] = 0.0f;
    for (int i = 0; i < deg; ++i) {
        int2 r = rec[start + i];
        unsigned packed = (unsigned)r.y;
        int s = (int)(packed >> 14);
        float m = (float)(packed & 16383u) * (1.0f / 16384.0f);
        const float4* hp = (const float4*)(h1 + (size_t)s * 32);
#pragma unroll
        for (int q = 0; q < 8; ++q) {
            float4 v = hp[q];
            x[4 * q + 0] += m * v.x;
            x[4 * q + 1] += m * v.y;
            x[4 * q + 2] += m * v.z;
            x[4 * q + 3] += m * v.w;
        }
    }
    float inv = 1.0f / fmaxf((float)deg, 1.0f);
#pragma unroll
    for (int j = 0; j < 32; ++j) x[j] *= inv;
    float hdn[32];
#pragma unroll
    for (int k = 0; k < 32; ++k) {
        float acc = sb2a[k];
#pragma unroll
        for (int j = 0; j < 32; ++j) acc += x[j] * sW2a[j * 32 + k];
        hdn[k] = fmaxf(acc, 0.0f);
    }
    int lane = threadIdx.x & 63;
#pragma unroll
    for (int k2 = 0; k2 < 32; ++k2) {
        float acc = sb2b[k2];
#pragma unroll
        for (int k = 0; k < 32; ++k) acc += hdn[k] * sW2b[k * 32 + k2];
        float v = valid ? fmaxf(acc, 0.0f) : 0.0f;
#pragma unroll
        for (int o = 32; o >= 1; o >>= 1)
            v = fmaxf(v, __shfl_xor(v, o));
        if (lane == 0) atomicMax(&smax[k2], __float_as_int(v));
    }
    __syncthreads();
    if (threadIdx.x < 32) atomicMax((int*)&gmax[threadIdx.x], smax[threadIdx.x]);
}

// ---------------- readout ----------------
__global__ void readout(const float* __restrict__ gmax,
                        const float* __restrict__ Wm1, const float* __restrict__ bm1,
                        const float* __restrict__ Wm2, const float* __restrict__ bm2,
                        float* __restrict__ out) {
    __shared__ float p[16];
    int t = threadIdx.x;
    if (t < 16) {
        float acc = bm1[t];
        for (int j = 0; j < 32; ++j) acc += gmax[j] * Wm1[j * 16 + t];
        p[t] = fmaxf(acc, 0.0f);
    }
    __syncthreads();
    if (t == 0) {
        float l0 = bm2[0], l1 = bm2[1];
        for (int k = 0; k < 16; ++k) { l0 += p[k] * Wm2[k * 2]; l1 += p[k] * Wm2[k * 2 + 1]; }
        float mx = fmaxf(l0, l1);
        float e0 = __expf(l0 - mx), e1 = __expf(l1 - mx);
        float s = e0 + e1;
        out[0] = e0 / s;
        out[1] = e1 / s;
    }
}

extern "C" void kernel_launch(void* const* d_in, const int* in_sizes, int n_in,
                              void* d_out, int out_size, void* d_ws, size_t ws_size,
                              hipStream_t stream) {
    const float* node_feat = (const float*)d_in[0];
    const float* edge_feat = (const float*)d_in[1];
    const float* edge_mask = (const float*)d_in[2];
    const int*   src       = (const int*)d_in[3];
    const int*   dst       = (const int*)d_in[4];
    const float* W1a = (const float*)d_in[5];
    const float* b1a = (const float*)d_in[6];
    const float* W1b = (const float*)d_in[7];
    const float* b1b = (const float*)d_in[8];
    const float* W2a = (const float*)d_in[9];
    const float* b2a = (const float*)d_in[10];
    const float* W2b = (const float*)d_in[11];
    const float* b2b = (const float*)d_in[12];
    const float* Wm1 = (const float*)d_in[13];
    const float* bm1 = (const float*)d_in[14];
    const float* Wm2 = (const float*)d_in[15];
    const float* bm2 = (const float*)d_in[16];

    const int N = in_sizes[0] / 7;   // 200000
    const int E = in_sizes[3];       // 6400000

    // common head: deg_i[N] | gmax[32] | off[N+1]
    int*   deg_i = (int*)d_ws;
    float* gmax  = (float*)(deg_i + N);
    int*   off   = (int*)(gmax + 32);
    int*   slot  = off + (N + 1);       // rank during fill, then h1/h1h after

    // Plan A16 layout: slot16 = max(E, 16N) ints, then rec16[E] int4, then nf16[N] int4
    const size_t slot16 = (size_t)E > (size_t)16 * N ? (size_t)E : (size_t)16 * N;
    int*    rank   = slot;
    __half* h1h    = (__half*)slot;
    int4*   rec16  = (int4*)(slot + slot16);
    int4*   nf16   = rec16 + E;
    const size_t need16 = ((size_t)2 * N + 33 + slot16 + (size_t)E * 4 + (size_t)N * 4) * sizeof(int);

    // Plan A8 layout (round-3, proven to fit): slot8 = max(E, 32N) ints, then rec8[E] int2
    const size_t slot8 = (size_t)E > (size_t)32 * N ? (size_t)E : (size_t)32 * N;
    float* h1f  = (float*)slot;
    int2*  rec8 = (int2*)(slot + slot8);
    const size_t need8 = ((size_t)2 * N + 33 + slot8 + (size_t)E * 2) * sizeof(int);
    (void)need8;

    // zero deg_i + gmax (contiguous head)
    hipMemsetAsync(d_ws, 0, (size_t)(N + 32) * sizeof(int), stream);

    hist_rank<<<(E + 255) / 256, 256, 0, stream>>>(dst, deg_i, rank, E);
    scan_deg<<<1, 1024, 0, stream>>>(deg_i, off, N);

    if (ws_size >= need16) {
        pack_nodes<<<(N + 255) / 256, 256, 0, stream>>>(node_feat, nf16, N);
        fill_rec16<<<(E + 255) / 256, 256, 0, stream>>>(dst, rank, off, edge_mask, src,
                                                        edge_feat, rec16, E);
        agg1_16<<<(N + 255) / 256, 256, 0, stream>>>(rec16, off, nf16,
                                                     W1a, b1a, W1b, b1b, h1h, N);
        agg2_16<<<(N + 255) / 256, 256, 0, stream>>>(rec16, off, h1h,
                                                     W2a, b2a, W2b, b2b, gmax, N);
    } else {
        fill_rec<<<(E + 255) / 256, 256, 0, stream>>>(dst, rank, off, edge_mask, src, rec8, E);
        agg1_rec<<<(N + 255) / 256, 256, 0, stream>>>(rec8, off, edge_feat, node_feat,
                                                      W1a, b1a, W1b, b1b, h1f, N);
        agg2_rec<<<(N + 255) / 256, 256, 0, stream>>>(rec8, off, h1f,
                                                      W2a, b2a, W2b, b2b, gmax, N);
    }
    readout<<<1, 64, 0, stream>>>(gmax, Wm1, bm1, Wm2, bm2, (float*)d_out);
}

// Round 5
// 1177.539 us; speedup vs baseline: 7.9389x; 1.2324x over previous
//
#include <hip/hip_runtime.h>
#include <hip/hip_fp16.h>
#include <math.h>

#define SCHUNK 1024   // elements per scan block (256 threads x 4)

__device__ __forceinline__ float sigmoidf_(float x) {
    return 1.0f / (1.0f + __expf(-x));
}

union I2H { int i; __half2 h; };
__device__ __forceinline__ int pack_h2(float a, float b) {
    I2H u; u.h = __floats2half2_rn(a, b); return u.i;
}
__device__ __forceinline__ float2 unpack_h2(int w) {
    I2H u; u.i = w; return __half22float2(u.h);
}

// ---------------- hist + rank ----------------
__global__ void hist_rank(const int* __restrict__ dst, int* __restrict__ deg,
                          int* __restrict__ rank, int E) {
    int e = blockIdx.x * blockDim.x + threadIdx.x;
    if (e < E) rank[e] = atomicAdd(&deg[dst[e]], 1);
}

// ---------------- parallel scan, 3 kernels ----------------
__global__ void scan_part(const int* __restrict__ deg, int* __restrict__ bsum, int N) {
    __shared__ int tot[256];
    int t = threadIdx.x;
    int base = blockIdx.x * SCHUNK + t * 4;
    int s = 0;
    if (base + 3 < N) {
        int4 v = *(const int4*)(deg + base);
        s = v.x + v.y + v.z + v.w;
    } else {
#pragma unroll
        for (int j = 0; j < 4; ++j) if (base + j < N) s += deg[base + j];
    }
    tot[t] = s;
    __syncthreads();
    for (int o = 128; o >= 1; o >>= 1) {
        if (t < o) tot[t] += tot[t + o];
        __syncthreads();
    }
    if (t == 0) bsum[blockIdx.x] = tot[0];
}

__global__ void scan_mid(int* __restrict__ bsum, int* __restrict__ off, int B, int N) {
    __shared__ int tmp[256];
    int t = threadIdx.x;
    int chunk = (B + 255) / 256;
    int lo = t * chunk, hi = min(lo + chunk, B);
    int s = 0;
    for (int i = lo; i < hi; ++i) s += bsum[i];
    tmp[t] = s;
    __syncthreads();
    for (int o = 1; o < 256; o <<= 1) {
        int v = (t >= o) ? tmp[t - o] : 0;
        __syncthreads();
        tmp[t] += v;
        __syncthreads();
    }
    int run = (t == 0) ? 0 : tmp[t - 1];
    for (int i = lo; i < hi; ++i) { int d = bsum[i]; bsum[i] = run; run += d; }
    if (t == 255) off[N] = tmp[255];
}

__global__ void scan_fin(const int* __restrict__ deg, const int* __restrict__ bsum,
                         int* __restrict__ off, int N) {
    __shared__ int tots[256];
    int t = threadIdx.x;
    int base = blockIdx.x * SCHUNK + t * 4;
    int v0 = 0, v1 = 0, v2 = 0, v3 = 0;
    if (base + 3 < N) {
        int4 v = *(const int4*)(deg + base);
        v0 = v.x; v1 = v.y; v2 = v.z; v3 = v.w;
    } else {
        if (base + 0 < N) v0 = deg[base + 0];
        if (base + 1 < N) v1 = deg[base + 1];
        if (base + 2 < N) v2 = deg[base + 2];
        if (base + 3 < N) v3 = deg[base + 3];
    }
    tots[t] = v0 + v1 + v2 + v3;
    __syncthreads();
    for (int o = 1; o < 256; o <<= 1) {
        int v = (t >= o) ? tots[t - o] : 0;
        __syncthreads();
        tots[t] += v;
        __syncthreads();
    }
    int run = bsum[blockIdx.x] + ((t == 0) ? 0 : tots[t - 1]);
    if (base + 0 < N) off[base + 0] = run; run += v0;
    if (base + 1 < N) off[base + 1] = run; run += v1;
    if (base + 2 < N) off[base + 2] = run; run += v2;
    if (base + 3 < N) off[base + 3] = run;
}

// ======================= Plan A16: 16B records {src, h2(m*ef01), h2(m*ef23), m} =======================
__global__ void pack_nodes(const float* __restrict__ nf, int4* __restrict__ nf16, int N) {
    int n = blockIdx.x * blockDim.x + threadIdx.x;
    if (n >= N) return;
    const float* p = nf + (size_t)n * 7;
    int4 w;
    w.x = pack_h2(p[0], p[1]);
    w.y = pack_h2(p[2], p[3]);
    w.z = pack_h2(p[4], p[5]);
    w.w = pack_h2(p[6], 0.0f);
    nf16[n] = w;
}

__global__ void fill_rec16(const int* __restrict__ dst, const int* __restrict__ rank,
                           const int* __restrict__ off,
                           const float* __restrict__ edge_mask,
                           const int* __restrict__ src,
                           const float* __restrict__ edge_feat,
                           int4* __restrict__ rec, int E) {
    int e = blockIdx.x * blockDim.x + threadIdx.x;
    if (e >= E) return;
    int p = off[dst[e]] + rank[e];          // no atomics
    float m = sigmoidf_(edge_mask[e >> 1]);
    float4 ef = *(const float4*)(edge_feat + (size_t)e * 4);
    int4 w;
    w.x = src[e];
    w.y = pack_h2(m * ef.x, m * ef.y);
    w.z = pack_h2(m * ef.z, m * ef.w);
    w.w = __float_as_int(m);
    rec[p] = w;
}

__global__ void agg1_16(const int4* __restrict__ rec, const int* __restrict__ off,
                        const int4* __restrict__ nf16,
                        const float* __restrict__ W1a, const float* __restrict__ b1a,
                        const float* __restrict__ W1b, const float* __restrict__ b1b,
                        __half* __restrict__ h1h, int N) {
    __shared__ float sW1a[11 * 32], sb1a[32], sW1b[32 * 32], sb1b[32];
    for (int i = threadIdx.x; i < 11 * 32; i += blockDim.x) sW1a[i] = W1a[i];
    for (int i = threadIdx.x; i < 32 * 32; i += blockDim.x) sW1b[i] = W1b[i];
    if (threadIdx.x < 32) { sb1a[threadIdx.x] = b1a[threadIdx.x]; sb1b[threadIdx.x] = b1b[threadIdx.x]; }
    __syncthreads();
    int n = blockIdx.x * blockDim.x + threadIdx.x;
    if (n >= N) return;
    int start = off[n];
    int deg = off[n + 1] - start;
    float x[11];
#pragma unroll
    for (int j = 0; j < 11; ++j) x[j] = 0.0f;
    for (int i = 0; i < deg; ++i) {
        int4 r = rec[start + i];
        float m = __int_as_float(r.w);
        float2 e01 = unpack_h2(r.y), e23 = unpack_h2(r.z);
        x[0] += e01.x; x[1] += e01.y; x[2] += e23.x; x[3] += e23.y;
        int4 nw = nf16[r.x];
        float2 n01 = unpack_h2(nw.x), n23 = unpack_h2(nw.y);
        float2 n45 = unpack_h2(nw.z), n6 = unpack_h2(nw.w);
        x[4] += m * n01.x; x[5]  += m * n01.y; x[6] += m * n23.x; x[7] += m * n23.y;
        x[8] += m * n45.x; x[9]  += m * n45.y; x[10] += m * n6.x;
    }
    float inv = 1.0f / fmaxf((float)deg, 1.0f);
#pragma unroll
    for (int j = 0; j < 11; ++j) x[j] *= inv;
    float hdn[32];
#pragma unroll
    for (int k = 0; k < 32; ++k) {
        float acc = sb1a[k];
#pragma unroll
        for (int j = 0; j < 11; ++j) acc += x[j] * sW1a[j * 32 + k];
        hdn[k] = fmaxf(acc, 0.0f);
    }
    float o[32];
#pragma unroll
    for (int k2 = 0; k2 < 32; ++k2) {
        float acc = sb1b[k2];
#pragma unroll
        for (int k = 0; k < 32; ++k) acc += hdn[k] * sW1b[k * 32 + k2];
        o[k2] = fmaxf(acc, 0.0f);
    }
    int4* outp = (int4*)(h1h + (size_t)n * 32);
#pragma unroll
    for (int q = 0; q < 4; ++q) {
        int4 w;
        w.x = pack_h2(o[8 * q + 0], o[8 * q + 1]);
        w.y = pack_h2(o[8 * q + 2], o[8 * q + 3]);
        w.z = pack_h2(o[8 * q + 4], o[8 * q + 5]);
        w.w = pack_h2(o[8 * q + 6], o[8 * q + 7]);
        outp[q] = w;
    }
}

__global__ void agg2_16(const int4* __restrict__ rec, const int* __restrict__ off,
                        const __half* __restrict__ h1h,
                        const float* __restrict__ W2a, const float* __restrict__ b2a,
                        const float* __restrict__ W2b, const float* __restrict__ b2b,
                        float* __restrict__ gmax, int N) {
    __shared__ float sW2a[32 * 32], sb2a[32], sW2b[32 * 32], sb2b[32];
    __shared__ int smax[32];
    for (int i = threadIdx.x; i < 32 * 32; i += blockDim.x) { sW2a[i] = W2a[i]; sW2b[i] = W2b[i]; }
    if (threadIdx.x < 32) {
        sb2a[threadIdx.x] = b2a[threadIdx.x];
        sb2b[threadIdx.x] = b2b[threadIdx.x];
        smax[threadIdx.x] = 0;
    }
    __syncthreads();
    int n = blockIdx.x * blockDim.x + threadIdx.x;
    bool valid = (n < N);
    int nn = valid ? n : 0;
    int start = valid ? off[nn] : 0;
    int deg = valid ? (off[nn + 1] - start) : 0;
    float x[32];
#pragma unroll
    for (int j = 0; j < 32; ++j) x[j] = 0.0f;
    for (int i = 0; i < deg; ++i) {
        int4 r = rec[start + i];
        int s = r.x;
        float m = __int_as_float(r.w);
        const int4* hp = (const int4*)(h1h + (size_t)s * 32);
#pragma unroll
        for (int q = 0; q < 4; ++q) {
            int4 v = hp[q];
            float2 a = unpack_h2(v.x), b = unpack_h2(v.y);
            float2 c = unpack_h2(v.z), d = unpack_h2(v.w);
            x[8 * q + 0] += m * a.x; x[8 * q + 1] += m * a.y;
            x[8 * q + 2] += m * b.x; x[8 * q + 3] += m * b.y;
            x[8 * q + 4] += m * c.x; x[8 * q + 5] += m * c.y;
            x[8 * q + 6] += m * d.x; x[8 * q + 7] += m * d.y;
        }
    }
    float inv = 1.0f / fmaxf((float)deg, 1.0f);
#pragma unroll
    for (int j = 0; j < 32; ++j) x[j] *= inv;
    float hdn[32];
#pragma unroll
    for (int k = 0; k < 32; ++k) {
        float acc = sb2a[k];
#pragma unroll
        for (int j = 0; j < 32; ++j) acc += x[j] * sW2a[j * 32 + k];
        hdn[k] = fmaxf(acc, 0.0f);
    }
    int lane = threadIdx.x & 63;
#pragma unroll
    for (int k2 = 0; k2 < 32; ++k2) {
        float acc = sb2b[k2];
#pragma unroll
        for (int k = 0; k < 32; ++k) acc += hdn[k] * sW2b[k * 32 + k2];
        float v = valid ? fmaxf(acc, 0.0f) : 0.0f;
#pragma unroll
        for (int o = 32; o >= 1; o >>= 1)
            v = fmaxf(v, __shfl_xor(v, o));
        if (lane == 0) atomicMax(&smax[k2], __float_as_int(v));
    }
    __syncthreads();
    if (threadIdx.x < 32) atomicMax((int*)&gmax[threadIdx.x], smax[threadIdx.x]);
}

// ======================= Fallback Plan A8 (proven to fit) =======================
__global__ void fill_rec(const int* __restrict__ dst, const int* __restrict__ rank,
                         const int* __restrict__ off,
                         const float* __restrict__ edge_mask,
                         const int* __restrict__ src,
                         int2* __restrict__ rec, int E) {
    int e = blockIdx.x * blockDim.x + threadIdx.x;
    if (e >= E) return;
    int p = off[dst[e]] + rank[e];
    float m = sigmoidf_(edge_mask[e >> 1]);
    int mq = (int)(m * 16384.0f + 0.5f);
    mq = min(mq, 16383);
    unsigned packed = ((unsigned)src[e] << 14) | (unsigned)mq;
    rec[p] = make_int2(e, (int)packed);
}

__global__ void agg1_rec(const int2* __restrict__ rec, const int* __restrict__ off,
                         const float* __restrict__ edge_feat,
                         const float* __restrict__ node_feat,
                         const float* __restrict__ W1a, const float* __restrict__ b1a,
                         const float* __restrict__ W1b, const float* __restrict__ b1b,
                         float* __restrict__ h1, int N) {
    __shared__ float sW1a[11 * 32], sb1a[32], sW1b[32 * 32], sb1b[32];
    for (int i = threadIdx.x; i < 11 * 32; i += blockDim.x) sW1a[i] = W1a[i];
    for (int i = threadIdx.x; i < 32 * 32; i += blockDim.x) sW1b[i] = W1b[i];
    if (threadIdx.x < 32) { sb1a[threadIdx.x] = b1a[threadIdx.x]; sb1b[threadIdx.x] = b1b[threadIdx.x]; }
    __syncthreads();
    int n = blockIdx.x * blockDim.x + threadIdx.x;
    if (n >= N) return;
    int start = off[n];
    int deg = off[n + 1] - start;
    float x[11];
#pragma unroll
    for (int j = 0; j < 11; ++j) x[j] = 0.0f;
    for (int i = 0; i < deg; ++i) {
        int2 r = rec[start + i];
        int e = r.x;
        unsigned packed = (unsigned)r.y;
        int s = (int)(packed >> 14);
        float m = (float)(packed & 16383u) * (1.0f / 16384.0f);
        float4 ef = *(const float4*)(edge_feat + (size_t)e * 4);
        x[0] += m * ef.x; x[1] += m * ef.y; x[2] += m * ef.z; x[3] += m * ef.w;
        const float* nf = node_feat + (size_t)s * 7;
#pragma unroll
        for (int j = 0; j < 7; ++j) x[4 + j] += m * nf[j];
    }
    float inv = 1.0f / fmaxf((float)deg, 1.0f);
#pragma unroll
    for (int j = 0; j < 11; ++j) x[j] *= inv;
    float hdn[32];
#pragma unroll
    for (int k = 0; k < 32; ++k) {
        float acc = sb1a[k];
#pragma unroll
        for (int j = 0; j < 11; ++j) acc += x[j] * sW1a[j * 32 + k];
        hdn[k] = fmaxf(acc, 0.0f);
    }
    float o[32];
#pragma unroll
    for (int k2 = 0; k2 < 32; ++k2) {
        float acc = sb1b[k2];
#pragma unroll
        for (int k = 0; k < 32; ++k) acc += hdn[k] * sW1b[k * 32 + k2];
        o[k2] = fmaxf(acc, 0.0f);
    }
    float4* outp = (float4*)(h1 + (size_t)n * 32);
#pragma unroll
    for (int q = 0; q < 8; ++q)
        outp[q] = make_float4(o[4 * q], o[4 * q + 1], o[4 * q + 2], o[4 * q + 3]);
}

__global__ void agg2_rec(const int2* __restrict__ rec, const int* __restrict__ off,
                         const float* __restrict__ h1,
                         const float* __restrict__ W2a, const float* __restrict__ b2a,
                         const float* __restrict__ W2b, const float* __restrict__ b2b,
                         float* __restrict__ gmax, int N) {
    __shared__ float sW2a[32 * 32], sb2a[32], sW2b[32 * 32], sb2b[32];
    __shared__ int smax[32];
    for (int i = threadIdx.x; i < 32 * 32; i += blockDim.x) { sW2a[i] = W2a[i]; sW2b[i] = W2b[i]; }
    if (threadIdx.x < 32) {
        sb2a[threadIdx.x] = b2a[threadIdx.x];
        sb2b[threadIdx.x] = b2b[threadIdx.x];
        smax[threadIdx.x] = 0;
    }
    __syncthreads();
    int n = blockIdx.x * blockDim.x + threadIdx.x;
    bool valid = (n < N);
    int nn = valid ? n : 0;
    int start = valid ? off[nn] : 0;
    int deg = valid ? (off[nn + 1] - start) : 0;
    float x[32];
#pragma unroll
    for (int j = 0; j < 32; ++j) x[j] = 0.0f;
    for (int i = 0; i < deg; ++i) {
        int2 r = rec[start + i];
        unsigned packed = (unsigned)r.y;
        int s = (int)(packed >> 14);
        float m = (float)(packed & 16383u) * (1.0f / 16384.0f);
        const float4* hp = (const float4*)(h1 + (size_t)s * 32);
#pragma unroll
        for (int q = 0; q < 8; ++q) {
            float4 v = hp[q];
            x[4 * q + 0] += m * v.x;
            x[4 * q + 1] += m * v.y;
            x[4 * q + 2] += m * v.z;
            x[4 * q + 3] += m * v.w;
        }
    }
    float inv = 1.0f / fmaxf((float)deg, 1.0f);
#pragma unroll
    for (int j = 0; j < 32; ++j) x[j] *= inv;
    float hdn[32];
#pragma unroll
    for (int k = 0; k < 32; ++k) {
        float acc = sb2a[k];
#pragma unroll
        for (int j = 0; j < 32; ++j) acc += x[j] * sW2a[j * 32 + k];
        hdn[k] = fmaxf(acc, 0.0f);
    }
    int lane = threadIdx.x & 63;
#pragma unroll
    for (int k2 = 0; k2 < 32; ++k2) {
        float acc = sb2b[k2];
#pragma unroll
        for (int k = 0; k < 32; ++k) acc += hdn[k] * sW2b[k * 32 + k2];
        float v = valid ? fmaxf(acc, 0.0f) : 0.0f;
#pragma unroll
        for (int o = 32; o >= 1; o >>= 1)
            v = fmaxf(v, __shfl_xor(v, o));
        if (lane == 0) atomicMax(&smax[k2], __float_as_int(v));
    }
    __syncthreads();
    if (threadIdx.x < 32) atomicMax((int*)&gmax[threadIdx.x], smax[threadIdx.x]);
}

// ---------------- readout ----------------
__global__ void readout(const float* __restrict__ gmax,
                        const float* __restrict__ Wm1, const float* __restrict__ bm1,
                        const float* __restrict__ Wm2, const float* __restrict__ bm2,
                        float* __restrict__ out) {
    __shared__ float p[16];
    int t = threadIdx.x;
    if (t < 16) {
        float acc = bm1[t];
        for (int j = 0; j < 32; ++j) acc += gmax[j] * Wm1[j * 16 + t];
        p[t] = fmaxf(acc, 0.0f);
    }
    __syncthreads();
    if (t == 0) {
        float l0 = bm2[0], l1 = bm2[1];
        for (int k = 0; k < 16; ++k) { l0 += p[k] * Wm2[k * 2]; l1 += p[k] * Wm2[k * 2 + 1]; }
        float mx = fmaxf(l0, l1);
        float e0 = __expf(l0 - mx), e1 = __expf(l1 - mx);
        float s = e0 + e1;
        out[0] = e0 / s;
        out[1] = e1 / s;
    }
}

extern "C" void kernel_launch(void* const* d_in, const int* in_sizes, int n_in,
                              void* d_out, int out_size, void* d_ws, size_t ws_size,
                              hipStream_t stream) {
    const float* node_feat = (const float*)d_in[0];
    const float* edge_feat = (const float*)d_in[1];
    const float* edge_mask = (const float*)d_in[2];
    const int*   src       = (const int*)d_in[3];
    const int*   dst       = (const int*)d_in[4];
    const float* W1a = (const float*)d_in[5];
    const float* b1a = (const float*)d_in[6];
    const float* W1b = (const float*)d_in[7];
    const float* b1b = (const float*)d_in[8];
    const float* W2a = (const float*)d_in[9];
    const float* b2a = (const float*)d_in[10];
    const float* W2b = (const float*)d_in[11];
    const float* b2b = (const float*)d_in[12];
    const float* Wm1 = (const float*)d_in[13];
    const float* bm1 = (const float*)d_in[14];
    const float* Wm2 = (const float*)d_in[15];
    const float* bm2 = (const float*)d_in[16];

    const int N = in_sizes[0] / 7;   // 200000
    const int E = in_sizes[3];       // 6400000
    const int B = (N + SCHUNK - 1) / SCHUNK;   // scan blocks

    // common head: deg_i[N] | gmax[32] | off[N+1] | bsum[B+1]
    int*   deg_i = (int*)d_ws;
    float* gmax  = (float*)(deg_i + N);
    int*   off   = (int*)(gmax + 32);
    int*   bsum  = off + (N + 1);
    int*   slot  = bsum + (B + 1);      // rank during fill, then h1/h1h after

    // Plan A16 layout: slot16 = max(E, 16N) ints, then rec16[E] int4, then nf16[N] int4
    const size_t slot16 = (size_t)E > (size_t)16 * N ? (size_t)E : (size_t)16 * N;
    int*    rank   = slot;
    __half* h1h    = (__half*)slot;
    int4*   rec16  = (int4*)(slot + slot16);
    int4*   nf16   = rec16 + E;
    const size_t need16 = ((size_t)2 * N + 34 + B + slot16 + (size_t)E * 4 + (size_t)N * 4) * sizeof(int);

    // Plan A8 layout: slot8 = max(E, 32N) ints, then rec8[E] int2
    const size_t slot8 = (size_t)E > (size_t)32 * N ? (size_t)E : (size_t)32 * N;
    float* h1f  = (float*)slot;
    int2*  rec8 = (int2*)(slot + slot8);

    // zero deg_i + gmax (contiguous head)
    hipMemsetAsync(d_ws, 0, (size_t)(N + 32) * sizeof(int), stream);

    hist_rank<<<(E + 255) / 256, 256, 0, stream>>>(dst, deg_i, rank, E);
    scan_part<<<B, 256, 0, stream>>>(deg_i, bsum, N);
    scan_mid<<<1, 256, 0, stream>>>(bsum, off, B, N);
    scan_fin<<<B, 256, 0, stream>>>(deg_i, bsum, off, N);

    if (ws_size >= need16) {
        pack_nodes<<<(N + 255) / 256, 256, 0, stream>>>(node_feat, nf16, N);
        fill_rec16<<<(E + 255) / 256, 256, 0, stream>>>(dst, rank, off, edge_mask, src,
                                                        edge_feat, rec16, E);
        agg1_16<<<(N + 255) / 256, 256, 0, stream>>>(rec16, off, nf16,
                                                     W1a, b1a, W1b, b1b, h1h, N);
        agg2_16<<<(N + 255) / 256, 256, 0, stream>>>(rec16, off, h1h,
                                                     W2a, b2a, W2b, b2b, gmax, N);
    } else {
        fill_rec<<<(E + 255) / 256, 256, 0, stream>>>(dst, rank, off, edge_mask, src, rec8, E);
        agg1_rec<<<(N + 255) / 256, 256, 0, stream>>>(rec8, off, edge_feat, node_feat,
                                                      W1a, b1a, W1b, b1b, h1f, N);
        agg2_rec<<<(N + 255) / 256, 256, 0, stream>>>(rec8, off, h1f,
                                                      W2a, b2a, W2b, b2b, gmax, N);
    }
    readout<<<1, 64, 0, stream>>>(gmax, Wm1, bm1, Wm2, bm2, (float*)d_out);
}